// Round 12
// baseline (95.681 us; speedup 1.0000x reference)
//
#include <hip/hip_runtime.h>

// Problem constants (from reference)
constexpr int B_  = 16;
constexpr int NV_ = 10475;
constexpr int F_  = 20908;
constexpr int P_  = F_ * 8;              // 167264 pairs per batch
constexpr float LINEAR_MAX_ = 1000.0f;

constexpr int VP_PB_   = 41;             // vertex blocks per batch (41*256 >= NV_)
constexpr int REC_PB_  = 82;             // face-record blocks per batch
constexpr int PAIR_PB_ = 82;             // pair blocks per batch (8 pairs/thread)

// d_ws layout (~24.5 MB):
//   tbl    : 64 B per (b,f) record                     21.4 MB
//   vpack  : float4[B_*NV_]                             2.68 MB
//   faces4 : int4[F_]                                   0.33 MB
//   part   : float[B_*PAIR_PB_]
// Record (b,f): [0]{n.xyz, c·n} [1]{v0.xyz,v1.x} [2]{v1.yz,v2.xy} [3]{v2.z,-,-,-}

// XCD b-locality swizzle (consecutive bids round-robin the 8 XCDs): each XCD
// serves 2 batches -> per-XCD table slice 2.7 MB, L2-resident. Heuristic only.
__device__ __forceinline__ void swz(int bid, int& b, int& px) {
    const int xcd = bid & 7;
    const int j   = bid >> 3;
    b  = xcd + ((j & 1) << 3);
    px = j >> 1;
}

// Pass 0: pack vertices to float4 (aligned gathers later) + faces rows to int4.
__global__ __launch_bounds__(256) void pre_pack_kernel(
    const float* __restrict__ v,        // (B, NV, 3)
    const int*   __restrict__ faces,    // (F, 3)
    float4*      __restrict__ vpack,    // (B, NV)
    int4*        __restrict__ faces4)   // (F)
{
    const int bid = blockIdx.x;
    int b, px; swz(bid, b, px);
    const int t = threadIdx.x;

    const int g = bid * 256 + t;                 // linear, coalesced (first 82 blocks)
    if (g < F_)
        faces4[g] = make_int4(faces[g*3+0], faces[g*3+1], faces[g*3+2], 0);

    const int vid = px * 256 + t;
    if (vid < NV_) {
        const float* src = v + ((size_t)b * NV_ + vid) * 3;
        vpack[(size_t)b * NV_ + vid] = make_float4(src[0], src[1], src[2], 0.0f);
    }
}

// Pass 1: build 64B records from vpack/faces4 (4 scattered vector loads per
// thread instead of 12 scalars), stage in LDS, write coalesced.
__global__ __launch_bounds__(256) void face_rec_kernel(
    const float4* __restrict__ vpack,
    const int4*   __restrict__ faces4,
    float4*       __restrict__ tbl)
{
    __shared__ float4 lds4[1024];       // 256 records * 4 float4 = 16 KB

    int b, px; swz(blockIdx.x, b, px);
    const int t  = threadIdx.x;
    const int f0 = px * 256;
    const int f  = f0 + t;
    const int fc = (f < F_) ? f : 0;    // clamp tail

    const int4 fi = faces4[fc];
    const float4* __restrict__ vb = vpack + (size_t)b * NV_;
    const float4 p0 = vb[fi.x];
    const float4 p1 = vb[fi.y];
    const float4 p2 = vb[fi.z];

    const float third = 1.0f / 3.0f;
    const float cx = (p0.x + p1.x + p2.x) * third;
    const float cy = (p0.y + p1.y + p2.y) * third;
    const float cz = (p0.z + p1.z + p2.z) * third;

    const float e1x = p1.x - p0.x, e1y = p1.y - p0.y, e1z = p1.z - p0.z;
    const float e2x = p2.x - p0.x, e2y = p2.y - p0.y, e2z = p2.z - p0.z;
    float nx = e1y * e2z - e1z * e2y;
    float ny = e1z * e2x - e1x * e2z;
    float nz = e1x * e2y - e1y * e2x;
    const float inv = 1.0f / (sqrtf(nx * nx + ny * ny + nz * nz) + 1e-12f);
    nx *= inv; ny *= inv; nz *= inv;

    lds4[t * 4 + 0] = make_float4(nx, ny, nz, cx * nx + cy * ny + cz * nz);
    lds4[t * 4 + 1] = make_float4(p0.x, p0.y, p0.z, p1.x);
    lds4[t * 4 + 2] = make_float4(p1.y, p1.z, p2.x, p2.y);
    lds4[t * 4 + 3] = make_float4(p2.z, 0.0f, 0.0f, 0.0f);
    __syncthreads();

    // Coalesced write-out; guard tail so we never write past batch b's region.
    const int vrec  = F_ - f0;
    const int limit = ((vrec < 256) ? vrec : 256) * 4;
    float4* dst = tbl + ((size_t)b * F_ + f0) * 4;
    #pragma unroll
    for (int j = 0; j < 4; ++j) {
        const int e = j * 256 + t;
        if (e < limit) dst[e] = lds4[e];
    }
}

// Pass 2: 8 pairs per thread via 4 int4 loads (2 pairs each, coalesced).
// Per valid pair: 4 scattered float4 loads touching 2 cache lines. No atomics.
__global__ __launch_bounds__(256) void pen_pairs_kernel(
    const int*    __restrict__ coll,    // (B, P, 2) as ints
    const float4* __restrict__ tbl,
    float*        __restrict__ part)    // (B, PAIR_PB_)
{
    int b, px; swz(blockIdx.x, b, px);
    const int t = threadIdx.x;

    const int4*   __restrict__ c4 = (const int4*)(coll + (size_t)b * P_ * 2);
    const float4* __restrict__ bt = tbl + (size_t)b * F_ * 4;

    float psi2 = 0.0f;
    const int ibase = px * 1024;        // int4 index base (block covers 2048 pairs)

    #pragma unroll
    for (int k = 0; k < 4; ++k) {
        const int idx = ibase + (k << 8) + t;     // pairs 2*idx, 2*idx+1
        if (idx < (P_ >> 1)) {
            const int4 pp = c4[idx];

            #pragma unroll
            for (int h = 0; h < 2; ++h) {
                const int ix = (h == 0) ? pp.x : pp.z;   // intruder
                const int iy = (h == 0) ? pp.y : pp.w;   // receiver
                const float m = ((ix | iy) >= 0) ? 1.0f : 0.0f;
                const int fR = (iy > 0) ? iy : 0;
                const int fI = (ix > 0) ? ix : 0;

                const float4 nd = bt[fR * 4 + 0];
                const float4 L0 = bt[fI * 4 + 1];
                const float4 L1 = bt[fI * 4 + 2];
                const float4 L2 = bt[fI * 4 + 3];

                float s = 0.0f;
                float t0 = nd.w - (L0.x * nd.x + L0.y * nd.y + L0.z * nd.z);
                t0 = fminf(fmaxf(t0, 0.0f), LINEAR_MAX_);
                s = fmaf(t0, t0, s);
                float t1 = nd.w - (L0.w * nd.x + L1.x * nd.y + L1.y * nd.z);
                t1 = fminf(fmaxf(t1, 0.0f), LINEAR_MAX_);
                s = fmaf(t1, t1, s);
                float t2 = nd.w - (L1.z * nd.x + L1.w * nd.y + L2.x * nd.z);
                t2 = fminf(fmaxf(t2, 0.0f), LINEAR_MAX_);
                s = fmaf(t2, t2, s);

                psi2 = fmaf(m, s, psi2);
            }
        }
    }

    #pragma unroll
    for (int off = 32; off > 0; off >>= 1)
        psi2 += __shfl_down(psi2, off, 64);

    __shared__ float wsum[4];
    const int lane = t & 63;
    const int wid  = t >> 6;
    if (lane == 0) wsum[wid] = psi2;
    __syncthreads();

    if (t == 0)
        part[b * PAIR_PB_ + px] = wsum[0] + wsum[1] + wsum[2] + wsum[3];
}

// Pass 3: block b sums its 82 partials, writes out[b] (overwrites poison).
__global__ __launch_bounds__(128) void final_reduce_kernel(
    const float* __restrict__ part,     // (B, PAIR_PB_)
    float*       __restrict__ out)      // (B,)
{
    const int b = blockIdx.x;
    const int t = threadIdx.x;

    float s = (t < PAIR_PB_) ? part[b * PAIR_PB_ + t] : 0.0f;

    #pragma unroll
    for (int off = 32; off > 0; off >>= 1)
        s += __shfl_down(s, off, 64);

    __shared__ float wsum[2];
    if ((t & 63) == 0) wsum[t >> 6] = s;
    __syncthreads();

    if (t == 0) out[b] = wsum[0] + wsum[1];
}

extern "C" void kernel_launch(void* const* d_in, const int* in_sizes, int n_in,
                              void* d_out, int out_size, void* d_ws, size_t ws_size,
                              hipStream_t stream) {
    const float* v     = (const float*)d_in[0];
    const int*   faces = (const int*)d_in[1];
    const int*   coll  = (const int*)d_in[2];
    float* out = (float*)d_out;

    char* ws = (char*)d_ws;
    float4* tbl    = (float4*)ws;   ws += (size_t)B_ * F_ * 64;
    float4* vpack  = (float4*)ws;   ws += (size_t)B_ * NV_ * 16;
    int4*   faces4 = (int4*)ws;     ws += (size_t)F_ * 16;
    float*  part   = (float*)ws;

    dim3 block(256);
    pre_pack_kernel   <<<dim3(16 * VP_PB_),   block, 0, stream>>>(v, faces, vpack, faces4); // 656
    face_rec_kernel   <<<dim3(16 * REC_PB_),  block, 0, stream>>>(vpack, faces4, tbl);      // 1312
    pen_pairs_kernel  <<<dim3(16 * PAIR_PB_), block, 0, stream>>>(coll, tbl, part);         // 1312
    final_reduce_kernel<<<dim3(B_), dim3(128), 0, stream>>>(part, out);
}